// Round 3
// baseline (187.295 us; speedup 1.0000x reference)
//
#include <hip/hip_runtime.h>

#define B_ 2
#define C_ 3
#define H_ 512
#define W_ 512
#define F_ 5
#define T_ 25
#define HW_ (H_ * W_)
#define PW_ 520   // packed row stride in pixels (8B each)
#define PH_ 513   // packed rows; row 512 duplicates row 511 (border clamp)

// LDS tile geometry: block covers 64w x 4h outputs, halo +-10 px
#define TBW 64
#define TBH 4
#define RY  10
#define RX  10
#define TRH (TBH + 2 * RY + 1)   // 25 rows
#define TCW 89                   // ODD row stride: bank pair = (9*ty+tc)%16, rows spread
#define TILE_N (TRH * TCW)       // 2225 entries * 8B = 17.8 KB

// streaming loads: no reuse
#define NT(p) __builtin_nontemporal_load(p)

typedef _Float16 h4 __attribute__((ext_vector_type(4), aligned(8)));

// Repack planar f32 [B][C][H][W] -> fp16x4-packed [B][PH_][PW_] with
// duplicated clamp column (x=512 == x=511) and clamp row (row 512 == 511).
__global__ __launch_bounds__(256) void repack_kernel(
    const float* __restrict__ inp, h4* __restrict__ pk)
{
    const int x   = (blockIdx.x << 8) + threadIdx.x;   // 0..511
    const int row = blockIdx.y;                        // 0..512
    const int b   = blockIdx.z;
    const int sr  = row < H_ ? row : H_ - 1;
    const float* p = inp + b * (C_ * HW_) + (sr << 9) + x;
    h4 v;
    v.x = (_Float16)p[0];
    v.y = (_Float16)p[HW_];
    v.z = (_Float16)p[2 * HW_];
    v.w = (_Float16)0.f;
    h4* dst = pk + b * (PH_ * PW_) + row * PW_;
    dst[x] = v;
    if (x == W_ - 1) dst[W_] = v;   // duplicate clamp column
}

// Single-path LDS-tile gather kernel. Rolled fy loop (#pragma unroll 1)
// with an explicit one-batch software pipeline for the 15 offset/mask
// streams -> live set ~80 VGPR (occupancy up) and next-batch HBM latency
// hides under current-batch tap compute. TCW=89 (odd) spreads random ty
// rows across all 16 LDS bank pairs.
__global__ __launch_bounds__(256) void dsepconv_kernel(
    const h4* __restrict__ pk,       // packed input
    const float* __restrict__ vert,
    const float* __restrict__ horz,
    const float* __restrict__ offx,
    const float* __restrict__ offy,
    const float* __restrict__ mask,
    float* __restrict__ out)
{
    __shared__ h4 tile[TILE_N];

    const int tid  = threadIdx.x;
    const int lane = tid & 63;
    const int wv   = tid >> 6;                  // wave id 0..3
    const int h0   = blockIdx.y * TBH;
    const int w0b  = blockIdx.x * TBW;
    const int b    = blockIdx.z;
    const int h    = h0 + wv;
    const int w    = w0b + lane;

    const int hw = (h << 9) | w;

    const float* vb   = vert + b * (F_ * HW_) + hw;
    const float* hb   = horz + b * (F_ * HW_) + hw;
    const float* ob_x = offx + b * (T_ * HW_) + hw;
    const float* ob_y = offy + b * (T_ * HW_) + hw;
    const float* mb   = mask + b * (T_ * HW_) + hw;
    const h4* pb      = pk + b * (PH_ * PW_);

    // horizontal filter values (static index in unrolled fx loop)
    float hz[F_];
#pragma unroll
    for (int f = 0; f < F_; ++f) hz[f] = NT(hb + f * HW_);

    // pipeline prologue: batch 0 of the offset/mask streams
    float cy[F_], cx[F_], cm[F_];
#pragma unroll
    for (int fx = 0; fx < F_; ++fx) {
        cy[fx] = NT(ob_y + fx * HW_);
        cx[fx] = NT(ob_x + fx * HW_);
        cm[fx] = NT(mb   + fx * HW_);
    }

    // ---- stage input tile + halo into LDS (division-free) ----
    {
        const int colg0 = w0b - RX + lane;
        const int gc0 = min(max(colg0, 0), W_);
        const int gc1 = min(max(colg0 + 64, 0), W_);
#pragma unroll
        for (int r0 = 0; r0 < 7; ++r0) {
            const int r = r0 * 4 + wv;          // 0..27
            if (r < TRH) {
                const int gr = min(max(h0 - RY + r, 0), H_);  // 0..512
                const h4* src = pb + gr * PW_;
                tile[r * TCW + lane] = src[gc0];
                if (lane < TCW - 64)
                    tile[r * TCW + 64 + lane] = src[gc1];
            }
        }
    }
    __syncthreads();

    float acc0 = 0.f, acc1 = 0.f, acc2 = 0.f;

    // tap position relative to tile origin:
    //   ixf_tile = oy + (lane + RX + fx - 1.5), clamped to tile
    const float xbase = (float)(lane + RX) - 1.5f;
    const float ybase = (float)(wv + RY) - 1.5f;
    // Reference border clamp folded into tile coords:
    const float xlo = -0.5f - (float)(w0b - RX);
    const float xhi = ((float)W_ - 0.5f) - (float)(w0b - RX);
    const float ylo = -0.5f - (float)(h0 - RY);
    const float yhi = ((float)H_ - 0.5f) - (float)(h0 - RY);

#pragma unroll 1
    for (int fy = 0; fy < F_; ++fy) {
        // prefetch next batch (uniform branch)
        float ny[F_], nx2[F_], nm[F_];
        if (fy + 1 < F_) {
            const int nb = (fy + 1) * F_;
#pragma unroll
            for (int fx = 0; fx < F_; ++fx) {
                ny[fx]  = NT(ob_y + (nb + fx) * HW_);
                nx2[fx] = NT(ob_x + (nb + fx) * HW_);
                nm[fx]  = NT(mb   + (nb + fx) * HW_);
            }
        }

        const float vfy = NT(vb + fy * HW_);   // per-iter load avoids v[fy] scratch
        const float yb  = ybase + (float)fy;

#pragma unroll
        for (int fx = 0; fx < F_; ++fx) {
            const float oy = cy[fx];
            const float ox = cx[fx];
            const float m  = cm[fx];

            // tile-space sample coords with the reference border clamp
            float ixf = oy + (xbase + (float)fx);
            float iyf = ox + yb;
            ixf = fminf(fmaxf(ixf, xlo), xhi);
            iyf = fminf(fmaxf(iyf, ylo), yhi);

            float x0f = floorf(ixf), y0f = floorf(iyf);
            // floor==-1 at global border: all weight on left/top sample
            float wx1 = (ixf - x0f);
            float wy1 = (iyf - y0f);
            wx1 = (x0f < xlo) ? 0.f : wx1;
            wy1 = (y0f < ylo) ? 0.f : wy1;

            // branchless tile clamp (memory safety for ~1e-17 prob taps)
            const int tc = min(max((int)x0f, 0), TCW - 2);
            const int ty = min(max((int)y0f, 0), TRH - 2);

            const h4* p = &tile[ty * TCW + tc];
            const h4 t00 = p[0];
            const h4 t01 = p[1];
            const h4 t10 = p[TCW];
            const h4 t11 = p[TCW + 1];

            // fp16 packed bilinear: x-lerp then y-lerp, 3 cvts at the end
            const _Float16 wx1h = (_Float16)wx1;
            const _Float16 wx0h = (_Float16)1.f - wx1h;
            const _Float16 wy1h = (_Float16)wy1;
            const _Float16 wy0h = (_Float16)1.f - wy1h;
            const h4 wx0v = { wx0h, wx0h, wx0h, wx0h };
            const h4 wx1v = { wx1h, wx1h, wx1h, wx1h };
            const h4 wy0v = { wy0h, wy0h, wy0h, wy0h };
            const h4 wy1v = { wy1h, wy1h, wy1h, wy1h };

            const h4 rt = t00 * wx0v + t01 * wx1v;
            const h4 rb = t10 * wx0v + t11 * wx1v;
            const h4 r  = rt * wy0v + rb * wy1v;

            const float coef = vfy * hz[fx] * m;
            acc0 += coef * (float)r.x;
            acc1 += coef * (float)r.y;
            acc2 += coef * (float)r.z;
        }

        // rotate pipeline (static indices, stays in registers)
        if (fy + 1 < F_) {
#pragma unroll
            for (int fx = 0; fx < F_; ++fx) {
                cy[fx] = ny[fx];
                cx[fx] = nx2[fx];
                cm[fx] = nm[fx];
            }
        }
    }

    float* ob = out + b * (C_ * HW_) + hw;
    __builtin_nontemporal_store(acc0, ob);
    __builtin_nontemporal_store(acc1, ob + HW_);
    __builtin_nontemporal_store(acc2, ob + 2 * HW_);
}

extern "C" void kernel_launch(void* const* d_in, const int* in_sizes, int n_in,
                              void* d_out, int out_size, void* d_ws, size_t ws_size,
                              hipStream_t stream) {
    const float* inp  = (const float*)d_in[0];
    const float* vert = (const float*)d_in[1];
    const float* horz = (const float*)d_in[2];
    const float* offx = (const float*)d_in[3];
    const float* offy = (const float*)d_in[4];
    const float* mask = (const float*)d_in[5];
    float* out = (float*)d_out;
    h4* pk = (h4*)d_ws;   // B * 513 * 520 * 8B = 4.27 MB

    dim3 blockR(256), gridR(W_ / 256, PH_, B_);
    hipLaunchKernelGGL(repack_kernel, gridR, blockR, 0, stream, inp, pk);

    dim3 block(256);
    dim3 grid(W_ / TBW, H_ / TBH, B_);
    hipLaunchKernelGGL(dsepconv_kernel, grid, block, 0, stream,
                       pk, vert, horz, offx, offy, mask, out);
}